// Round 2
// baseline (346.632 us; speedup 1.0000x reference)
//
#include <hip/hip_runtime.h>
#include <hip/hip_bf16.h>

#define NH 16
#define DH 64
#define LL 2048
#define DM 1024
#define MASKED_SCORE -1.25e9f

typedef __attribute__((ext_vector_type(4))) float f32x4;
typedef __attribute__((ext_vector_type(8))) short bf16x8;
typedef __attribute__((ext_vector_type(4))) short bf16x4;

__device__ __forceinline__ short f2b(float x) {
    union { float f; unsigned u; } v; v.f = x;
    unsigned r = v.u + 0x7fffu + ((v.u >> 16) & 1u);
    return (short)(r >> 16);
}

__global__ __launch_bounds__(256) void mha_fwd(
    const float* __restrict__ Q, const float* __restrict__ K,
    const float* __restrict__ V, const void* __restrict__ mask,
    float* __restrict__ out)
{
    const int qblk = blockIdx.x;
    const int h = blockIdx.y;
    const int b = blockIdx.z;
    const int tid = threadIdx.x;
    const int w = tid >> 6;
    const int lane = tid & 63;
    const int lq = lane & 15;     // q-row within 16-row strip (col of S^T)
    const int g = lane >> 4;      // 4-lane-group id 0..3

    // ---- mask dtype detection (uniform across all blocks/waves) ----
    // int32 layout: first 64 words are all 0 or 1. byte layout: words pack 4
    // random 0/1 bytes -> essentially surely some word > 1.
    const int* mw = (const int*)mask;
    unsigned long long bad = __ballot((unsigned)mw[lane] > 1u);
    const bool mask_is_int = (bad == 0ULL);

    const int qbase = qblk * 64 + w * 16;
    const float* Qp = Q + ((size_t)b * LL + qbase) * DM + h * DH;
    const float* Kp = K + (size_t)b * LL * DM + h * DH;
    const float* Vp = V + (size_t)b * LL * DM + h * DH;
    const unsigned char* Mp1 = (const unsigned char*)mask
                             + ((size_t)b * LL + qbase + lq) * (size_t)LL;
    const int* Mp4 = (const int*)mask
                   + ((size_t)b * LL + qbase + lq) * (size_t)LL;

    // V^T tile: [dv][key] bf16, 64 keys per stage; stride 68 (136B)
    __shared__ short Vt[64][68];

    // Q fragments (B-operand of S^T mfma): elem i -> Q[qbase+lq][32*half + 8g + i]
    bf16x8 qf[2];
    {
        const float* qrow = Qp + (size_t)lq * DM;
        #pragma unroll
        for (int half = 0; half < 2; ++half) {
            const float* src = qrow + half * 32 + g * 8;
            float4 a = *(const float4*)(src);
            float4 c = *(const float4*)(src + 4);
            qf[half][0] = f2b(a.x); qf[half][1] = f2b(a.y);
            qf[half][2] = f2b(a.z); qf[half][3] = f2b(a.w);
            qf[half][4] = f2b(c.x); qf[half][5] = f2b(c.y);
            qf[half][6] = f2b(c.z); qf[half][7] = f2b(c.w);
        }
    }

    f32x4 o[4];
    #pragma unroll
    for (int t = 0; t < 4; ++t) o[t] = (f32x4){0.f, 0.f, 0.f, 0.f};
    float m_run = -INFINITY;
    float l_run = 0.f;

    const int p_ = tid & 31;     // key-pair id for V staging
    const int dvg = tid >> 5;    // dv-group of 8 for V staging

    for (int kt = 0; kt < LL; kt += 64) {
        __syncthreads();
        {   // stage V^T (bf16) cooperatively: keys kt..kt+63, all 64 dv
            const float* v0 = Vp + (size_t)(kt + 2 * p_) * DM + dvg * 8;
            float4 a0 = *(const float4*)(v0);
            float4 a1 = *(const float4*)(v0 + 4);
            float4 b0 = *(const float4*)(v0 + DM);
            float4 b1 = *(const float4*)(v0 + DM + 4);
            float av[8] = {a0.x, a0.y, a0.z, a0.w, a1.x, a1.y, a1.z, a1.w};
            float bv[8] = {b0.x, b0.y, b0.z, b0.w, b1.x, b1.y, b1.z, b1.w};
            #pragma unroll
            for (int j = 0; j < 8; ++j) {
                unsigned u = (unsigned)(unsigned short)f2b(av[j])
                           | ((unsigned)(unsigned short)f2b(bv[j]) << 16);
                *(unsigned*)&Vt[8 * dvg + j][2 * p_] = u;
            }
        }
        __syncthreads();

        #pragma unroll
        for (int ki = 0; ki < 4; ++ki) {
            const int kb = kt + ki * 16;
            // K fragments (A-operand): same (g,i)->dk map as Q => layout-safe
            bf16x8 kf[2];
            const float* krow = Kp + (size_t)(kb + lq) * DM;
            #pragma unroll
            for (int half = 0; half < 2; ++half) {
                const float* src = krow + half * 32 + g * 8;
                float4 a = *(const float4*)(src);
                float4 c = *(const float4*)(src + 4);
                kf[half][0] = f2b(a.x); kf[half][1] = f2b(a.y);
                kf[half][2] = f2b(a.z); kf[half][3] = f2b(a.w);
                kf[half][4] = f2b(c.x); kf[half][5] = f2b(c.y);
                kf[half][6] = f2b(c.z); kf[half][7] = f2b(c.w);
            }
            // S^T[key][q] tile: lane holds q = lq, keys kb + 4g + r
            f32x4 s = (f32x4){0.f, 0.f, 0.f, 0.f};
            s = __builtin_amdgcn_mfma_f32_16x16x32_bf16(kf[0], qf[0], s, 0, 0, 0);
            s = __builtin_amdgcn_mfma_f32_16x16x32_bf16(kf[1], qf[1], s, 0, 0, 0);

            // mask bits for keys kb+4g+0..3, q-row lq (dual dtype path)
            unsigned mbits;
            if (mask_is_int) {
                int4 mi = *(const int4*)(Mp4 + kb + 4 * g);
                mbits = (mi.x ? 1u : 0u) | (mi.y ? 2u : 0u)
                      | (mi.z ? 4u : 0u) | (mi.w ? 8u : 0u);
            } else {
                unsigned mu = *(const unsigned*)(Mp1 + kb + 4 * g);
                mbits = (mu & 1u) | ((mu >> 7) & 2u)
                      | ((mu >> 14) & 4u) | ((mu >> 21) & 8u);
            }
            float sv[4];
            #pragma unroll
            for (int r = 0; r < 4; ++r)
                sv[r] = ((mbits >> r) & 1u) ? MASKED_SCORE : s[r] * 0.125f;

            // online softmax; row spread over lanes {lq, lq^16, lq^32, lq^48}
            float tmax = fmaxf(fmaxf(sv[0], sv[1]), fmaxf(sv[2], sv[3]));
            tmax = fmaxf(tmax, __shfl_xor(tmax, 16, 64));
            tmax = fmaxf(tmax, __shfl_xor(tmax, 32, 64));
            float newm = fmaxf(m_run, tmax);
            float alpha = __expf(m_run - newm);
            m_run = newm;
            float pv[4], psum = 0.f;
            #pragma unroll
            for (int r = 0; r < 4; ++r) { pv[r] = __expf(sv[r] - newm); psum += pv[r]; }
            l_run = l_run * alpha + psum;
            #pragma unroll
            for (int t = 0; t < 4; ++t) {
                o[t][0] *= alpha; o[t][1] *= alpha;
                o[t][2] *= alpha; o[t][3] *= alpha;
            }
            // P passes through in-lane as B-operand of 16x16x16 PV mfma
            bf16x4 pf;
            pf[0] = f2b(pv[0]); pf[1] = f2b(pv[1]);
            pf[2] = f2b(pv[2]); pf[3] = f2b(pv[3]);
            #pragma unroll
            for (int t = 0; t < 4; ++t) {
                bf16x4 vf = *(const bf16x4*)&Vt[16 * t + lq][ki * 16 + 4 * g];
                o[t] = __builtin_amdgcn_mfma_f32_16x16x16bf16_1k(vf, pf, o[t], 0, 0, 0);
            }
        }
    }

    // finish: sum l across the 4 lane-groups, normalize, store O^T
    l_run += __shfl_xor(l_run, 16, 64);
    l_run += __shfl_xor(l_run, 32, 64);
    float inv = 1.f / l_run;
    float* orow = out + ((size_t)b * LL + qbase + lq) * DM + h * DH;
    #pragma unroll
    for (int t = 0; t < 4; ++t) {
        float4 ov;
        ov.x = o[t][0] * inv; ov.y = o[t][1] * inv;
        ov.z = o[t][2] * inv; ov.w = o[t][3] * inv;
        *(float4*)(orow + 16 * t + 4 * g) = ov;
    }
}

extern "C" void kernel_launch(void* const* d_in, const int* in_sizes, int n_in,
                              void* d_out, int out_size, void* d_ws, size_t ws_size,
                              hipStream_t stream) {
    const float* Q = (const float*)d_in[0];
    const float* K = (const float*)d_in[1];
    const float* V = (const float*)d_in[2];
    const void* mask = d_in[3];
    float* out = (float*)d_out;
    dim3 grid(LL / 64, NH, 2);
    mha_fwd<<<grid, dim3(256), 0, stream>>>(Q, K, V, mask, out);
}

// Round 3
// 138.912 us; speedup vs baseline: 2.4953x; 2.4953x over previous
//
#include <hip/hip_runtime.h>
#include <hip/hip_bf16.h>

#define NH 16
#define DH 64
#define LL 2048
#define DM 1024
#define MASKED_SCORE -1.25e9f
#define DEFER_THR 8.0f

typedef __attribute__((ext_vector_type(4))) float f32x4;
typedef __attribute__((ext_vector_type(8))) short bf16x8;
typedef __attribute__((ext_vector_type(4))) short bf16x4;

__device__ __forceinline__ short f2b(float x) {
    union { float f; unsigned u; } v; v.f = x;
    unsigned r = v.u + 0x7fffu + ((v.u >> 16) & 1u);
    return (short)(r >> 16);
}

// ---- mask pre-pack: [B][L][L] (int32 or byte bool) -> bit per key ----
// bits[(b*LL+q)*64 + w] bit j = mask[b][q][32w+j] != 0
__global__ __launch_bounds__(256) void pack_mask(const void* __restrict__ mask,
                                                 unsigned* __restrict__ bits)
{
    const int tid = threadIdx.x;
    const int lane = tid & 63;
    // dtype detection (wave-uniform, identical across all blocks):
    // int32 bools -> first 64 words all in {0,1}; byte bools -> ~surely not.
    const int* mw = (const int*)mask;
    unsigned long long bad = __ballot((unsigned)mw[lane] > 1u);
    const bool is_int = (bad == 0ULL);

    const int wid = blockIdx.x * 256 + tid;   // 0 .. 2*LL*64-1
    const int q64 = wid >> 6;                 // b*LL + q
    const int w = wid & 63;
    unsigned m = 0;
    if (is_int) {
        const int* p = (const int*)mask + (size_t)q64 * LL + w * 32;
        #pragma unroll
        for (int j = 0; j < 32; j += 4) {
            int4 v = *(const int4*)(p + j);
            m |= (v.x ? 1u : 0u) << j;
            m |= (v.y ? 1u : 0u) << (j + 1);
            m |= (v.z ? 1u : 0u) << (j + 2);
            m |= (v.w ? 1u : 0u) << (j + 3);
        }
    } else {
        const unsigned* p = (const unsigned*)((const unsigned char*)mask
                                              + (size_t)q64 * LL + w * 32);
        #pragma unroll
        for (int j = 0; j < 8; ++j) {
            unsigned v = p[j];
            m |= (v & 1u) << (4 * j);
            m |= ((v >> 8) & 1u) << (4 * j + 1);
            m |= ((v >> 16) & 1u) << (4 * j + 2);
            m |= ((v >> 24) & 1u) << (4 * j + 3);
        }
    }
    bits[wid] = m;
}

__global__ __launch_bounds__(256) void mha_fwd(
    const float* __restrict__ Q, const float* __restrict__ K,
    const float* __restrict__ V, const unsigned* __restrict__ mbits,
    float* __restrict__ out)
{
    const int qblk = blockIdx.x;
    const int h = blockIdx.y;
    const int b = blockIdx.z;
    const int tid = threadIdx.x;
    const int w = tid >> 6;
    const int lane = tid & 63;
    const int lq = lane & 15;     // q-row within strip (col of S^T)
    const int g = lane >> 4;      // 4-lane-group 0..3

    const int qbase = qblk * 64 + w * 16;
    const float* Qp = Q + ((size_t)b * LL + qbase) * DM + h * DH;
    const float* Kp = K + (size_t)b * LL * DM + h * DH;
    const float* Vp = V + (size_t)b * LL * DM + h * DH;
    const unsigned* Wp = mbits + ((size_t)b * LL + qbase + lq) * 64;

    // K tile [key][dk] bf16, stride 72 shorts (144 B): rows land on distinct
    // bank groups for the strided 16-lane ds_read_b128 pattern.
    __shared__ short Kt[64][72];
    // V^T tile [dv][key] bf16, stride 68 (136 B): conflict-free ds_read_b64.
    __shared__ short Vt[64][68];

    // Q fragments: qf[half][i] = Q[qbase+lq][32*half + 8g + i]
    bf16x8 qf[2];
    {
        const float* qrow = Qp + (size_t)lq * DM;
        #pragma unroll
        for (int half = 0; half < 2; ++half) {
            const float* src = qrow + half * 32 + g * 8;
            float4 a = *(const float4*)(src);
            float4 c = *(const float4*)(src + 4);
            qf[half][0] = f2b(a.x); qf[half][1] = f2b(a.y);
            qf[half][2] = f2b(a.z); qf[half][3] = f2b(a.w);
            qf[half][4] = f2b(c.x); qf[half][5] = f2b(c.y);
            qf[half][6] = f2b(c.z); qf[half][7] = f2b(c.w);
        }
    }

    f32x4 o[4];
    #pragma unroll
    for (int t = 0; t < 4; ++t) o[t] = (f32x4){0.f, 0.f, 0.f, 0.f};
    float m_run = -INFINITY;
    float l_run = 0.f;

    const int skey = tid >> 2;          // K staging: key row
    const int sdq = (tid & 3) * 16;     // K staging: dk quarter
    const int p_ = tid & 31;            // V staging: key pair
    const int dvg = tid >> 5;           // V staging: dv group of 8

    for (int kt = 0; kt < LL; kt += 64) {
        __syncthreads();
        {   // stage K tile: 64 keys x 64 dk, converted to bf16 once per block
            const float* src = Kp + (size_t)(kt + skey) * DM + sdq;
            float4 a = *(const float4*)(src);
            float4 c = *(const float4*)(src + 4);
            float4 e = *(const float4*)(src + 8);
            float4 f = *(const float4*)(src + 12);
            bf16x8 lo, hi;
            lo[0] = f2b(a.x); lo[1] = f2b(a.y); lo[2] = f2b(a.z); lo[3] = f2b(a.w);
            lo[4] = f2b(c.x); lo[5] = f2b(c.y); lo[6] = f2b(c.z); lo[7] = f2b(c.w);
            hi[0] = f2b(e.x); hi[1] = f2b(e.y); hi[2] = f2b(e.z); hi[3] = f2b(e.w);
            hi[4] = f2b(f.x); hi[5] = f2b(f.y); hi[6] = f2b(f.z); hi[7] = f2b(f.w);
            *(bf16x8*)&Kt[skey][sdq] = lo;
            *(bf16x8*)&Kt[skey][sdq + 8] = hi;
        }
        {   // stage V^T tile
            const float* v0 = Vp + (size_t)(kt + 2 * p_) * DM + dvg * 8;
            float4 a0 = *(const float4*)(v0);
            float4 a1 = *(const float4*)(v0 + 4);
            float4 b0 = *(const float4*)(v0 + DM);
            float4 b1 = *(const float4*)(v0 + DM + 4);
            float av[8] = {a0.x, a0.y, a0.z, a0.w, a1.x, a1.y, a1.z, a1.w};
            float bv[8] = {b0.x, b0.y, b0.z, b0.w, b1.x, b1.y, b1.z, b1.w};
            #pragma unroll
            for (int j = 0; j < 8; ++j) {
                unsigned u = (unsigned)(unsigned short)f2b(av[j])
                           | ((unsigned)(unsigned short)f2b(bv[j]) << 16);
                *(unsigned*)&Vt[8 * dvg + j][2 * p_] = u;
            }
        }
        __syncthreads();

        // mask bits for this lane's q-row, keys kt..kt+63
        unsigned long long m64 = *(const unsigned long long*)(Wp + (kt >> 5));

        // ---- all 8 S^T MFMAs up front (ILP), then one softmax pass ----
        f32x4 s[4];
        #pragma unroll
        for (int ki = 0; ki < 4; ++ki) {
            bf16x8 k0 = *(const bf16x8*)&Kt[ki * 16 + lq][8 * g];
            bf16x8 k1 = *(const bf16x8*)&Kt[ki * 16 + lq][32 + 8 * g];
            f32x4 acc = (f32x4){0.f, 0.f, 0.f, 0.f};
            acc = __builtin_amdgcn_mfma_f32_16x16x32_bf16(k0, qf[0], acc, 0, 0, 0);
            acc = __builtin_amdgcn_mfma_f32_16x16x32_bf16(k1, qf[1], acc, 0, 0, 0);
            s[ki] = acc;
        }

        float sv[16];
        float pmax = -INFINITY;
        #pragma unroll
        for (int ki = 0; ki < 4; ++ki) {
            unsigned mb = (unsigned)(m64 >> (ki * 16 + 4 * g)) & 0xfu;
            #pragma unroll
            for (int r = 0; r < 4; ++r) {
                float x = ((mb >> r) & 1u) ? MASKED_SCORE : s[ki][r] * 0.125f;
                sv[ki * 4 + r] = x;
                pmax = fmaxf(pmax, x);
            }
        }
        pmax = fmaxf(pmax, __shfl_xor(pmax, 16, 64));
        pmax = fmaxf(pmax, __shfl_xor(pmax, 32, 64));

        // defer-max: rescale at most once per 64-key tile, skip when bounded
        if (!__all(pmax - m_run <= DEFER_THR)) {
            float newm = fmaxf(m_run, pmax);
            float alpha = __expf(m_run - newm);
            m_run = newm;
            l_run *= alpha;
            #pragma unroll
            for (int t = 0; t < 4; ++t) {
                o[t][0] *= alpha; o[t][1] *= alpha;
                o[t][2] *= alpha; o[t][3] *= alpha;
            }
        }

        float psum = 0.f;
        bf16x4 pf[4];
        #pragma unroll
        for (int ki = 0; ki < 4; ++ki) {
            #pragma unroll
            for (int r = 0; r < 4; ++r) {
                float p = __expf(sv[ki * 4 + r] - m_run);
                psum += p;
                pf[ki][r] = f2b(p);
            }
        }
        l_run += psum;

        #pragma unroll
        for (int ki = 0; ki < 4; ++ki) {
            #pragma unroll
            for (int t = 0; t < 4; ++t) {
                bf16x4 vf = *(const bf16x4*)&Vt[16 * t + lq][ki * 16 + 4 * g];
                o[t] = __builtin_amdgcn_mfma_f32_16x16x16bf16_1k(vf, pf[ki], o[t], 0, 0, 0);
            }
        }
    }

    // finish: sum l across the 4 lane-groups, normalize, store O^T
    l_run += __shfl_xor(l_run, 16, 64);
    l_run += __shfl_xor(l_run, 32, 64);
    float inv = 1.f / l_run;
    float* orow = out + ((size_t)b * LL + qbase + lq) * DM + h * DH;
    #pragma unroll
    for (int t = 0; t < 4; ++t) {
        float4 ov;
        ov.x = o[t][0] * inv; ov.y = o[t][1] * inv;
        ov.z = o[t][2] * inv; ov.w = o[t][3] * inv;
        *(float4*)(orow + 16 * t + 4 * g) = ov;
    }
}

extern "C" void kernel_launch(void* const* d_in, const int* in_sizes, int n_in,
                              void* d_out, int out_size, void* d_ws, size_t ws_size,
                              hipStream_t stream) {
    const float* Q = (const float*)d_in[0];
    const float* K = (const float*)d_in[1];
    const float* V = (const float*)d_in[2];
    const void* mask = d_in[3];
    float* out = (float*)d_out;
    unsigned* bits = (unsigned*)d_ws;   // 2*LL*64 u32 = 1 MB

    pack_mask<<<dim3(2 * LL * 64 / 256), dim3(256), 0, stream>>>(mask, bits);
    dim3 grid(LL / 64, NH, 2);
    mha_fwd<<<grid, dim3(256), 0, stream>>>(Q, K, V, bits, out);
}